// Round 13
// baseline (459.747 us; speedup 1.0000x reference)
//
#include <hip/hip_runtime.h>

// Per-sample depthwise 7x7 cross-correlation, NHWC, SAME padding.
// inputs:  [B,H,W,C] fp32, kernels: [B,7,7,C] fp32, out: [B,H,W,C] fp32.
// out[b,y,x,c] = sum_{i,j} in[b, y+i-3, x+j-3, c] * ker[b,i,j,c]  (zero pad)
//
// R13 = R8 (fp16 dot2, weights packed in LDS, 64-VGPR tier) + VALU-issue cuts:
//  - static accumulator-ring rotation over a 7-pass unroll; sched_barrier(0)
//    per pass body stops the cross-pass register ballooning that killed R9.
//    (kills 28 ring-shift v_movs per pass)
//  - tap loads rebased to column x0-1 so all 10 immediate offsets fit the
//    13-bit signed field -> 1 base add per pass instead of ~10 address adds.
//  - o[] packed pairs derived from e[] via v_alignbit.
// 35 main passes (5x7 static) + 3-pass canonical shifting tail (NPASS=38).

#define BB 32
#define HH 128
#define WW 128
#define CC 128
#define KH 7
#define KW 7

#define XPT 4                        // x outputs per thread
#define NTAP (XPT + KW - 1)          // 10 tap columns per thread
#define XG 8                         // x-groups per block (1024 threads / 128 c)
#define SLABW (XG * XPT)             // 32 output columns per block
#define NXS (WW / SLABW)             // 4 x-slabs
#define YSPLIT 4
#define YROWS (HH / YSPLIT)          // 32 output rows per block
#define GRID (BB * NXS * YSPLIT)     // 512 blocks = 2 per CU
#define WSLOTS 28                    // per-c packed-weight uints (7 rows x 4 pairs)
#define NPASS (YROWS + KH - 1)       // 38 passes = 5*7 static + 3 tail

typedef _Float16 half2_t __attribute__((ext_vector_type(2)));

static __device__ __forceinline__ half2_t pk(float a, float b) {
#if __has_builtin(__builtin_amdgcn_cvt_pkrtz)
    return __builtin_bit_cast(half2_t, __builtin_amdgcn_cvt_pkrtz(a, b));
#else
    half2_t r; r.x = (_Float16)a; r.y = (_Float16)b; return r;
#endif
}

static __device__ __forceinline__ float dot2f(unsigned w, half2_t t, float c) {
#if __has_builtin(__builtin_amdgcn_fdot2)
    return __builtin_amdgcn_fdot2(__builtin_bit_cast(half2_t, w), t, c, false);
#else
    half2_t wv = __builtin_bit_cast(half2_t, w);
    return fmaf((float)wv.x, (float)t.x, fmaf((float)wv.y, (float)t.y, c));
#endif
}

template <int N> struct ic { static constexpr int value = N; };

__global__ __launch_bounds__(1024) void crossconv_kernel(
    const float* __restrict__ in,
    const float* __restrict__ ker,
    float* __restrict__ out)
{
    __shared__ unsigned lds_w[CC * WSLOTS];   // 14336 B

    const int tid = threadIdx.x;
    const int c  = tid & (CC - 1);   // lanes contiguous in c -> coalesced
    const int xg = __builtin_amdgcn_readfirstlane(tid >> 7);   // 0..7, wave-uniform

    // Bijective XCD swizzle (GRID=512, 64 blocks/XCD = 4 whole samples).
    const int bid = blockIdx.x;
    const int swz = (bid & 7) * (GRID / 8) + (bid >> 3);
    const int b  = swz >> 4;         // 16 blocks per sample
    const int xs = (swz >> 2) & 3;
    const int yh = swz & 3;
    const int x0 = xs * SLABW + xg * XPT;  // wave-uniform (scalar)
    const int y0 = yh * YROWS;

    // Stage packed weights into LDS: slot s (0..27) -> row i=s>>2, pair q=s&3.
    // q<3: (w[i][2q], w[i][2q+1]); q==3: (w[i][6], 0).
    {
        const float* kb = ker + ((size_t)b * KH * KW) * CC + c;
        for (int s = xg; s < WSLOTS; s += XG) {
            const int i = s >> 2, q = s & 3;
            half2_t pr;
            if (q < 3) {
                const int f0 = i * KW + 2 * q;
                pr = pk(kb[f0 * CC], kb[(f0 + 1) * CC]);
            } else {
                pr = pk(kb[(i * KW + 6) * CC], 0.0f);
            }
            lds_w[c * WSLOTS + s] = __builtin_bit_cast(unsigned, pr);
        }
    }
    __syncthreads();

    const float* ib = in  + ((size_t)b * HH * WW) * CC;
    float*       ob = out + ((size_t)b * HH * WW) * CC;
    const unsigned* wlds = &lds_w[c * WSLOTS];

    const bool interior = (x0 >= 3) && (x0 + XPT + 2 < WW);

    // Issue the 10 tap loads for row yi. Base rebased to column x0-1 so the
    // per-tap offsets (j-2)*512 B fall in [-1024, 3584] -> 13-bit immediates.
    auto issue_taps = [&](float* t, int yi) {
        if (yi < 0 || yi >= HH) {
            #pragma unroll
            for (int j = 0; j < NTAP; ++j) t[j] = 0.0f;
            return;
        }
        const float* base = ib + (size_t)yi * WW * CC + (x0 - 1) * CC + c;
        if (interior) {
            #pragma unroll
            for (int j = 0; j < NTAP; ++j)
                t[j] = base[(j - 2) * CC];                 // imm offsets
        } else {
            #pragma unroll
            for (int j = 0; j < NTAP; ++j) {
                const int xx = x0 - 3 + j;
                t[j] = (xx >= 0 && xx < WW) ? base[(j - 2) * CC] : 0.0f;
            }
        }
    };

    float acc[KH][XPT];
    #pragma unroll
    for (int s = 0; s < KH; ++s)
        #pragma unroll
        for (int xo = 0; xo < XPT; ++xo) acc[s][xo] = 0.0f;

    const int yi0 = y0 - 3;

    // Packed taps for the CURRENT pass row:
    // e[k]=(t[2k],t[2k+1]) k=0..4 ; o[k]=(t[2k+1],t[2k+2]) via alignbit.
    half2_t e[5], o[5];
    float t[NTAP];

    auto pack = [&]() {
        #pragma unroll
        for (int k = 0; k < 5; ++k) e[k] = pk(t[2 * k], t[2 * k + 1]);
        #pragma unroll
        for (int k = 0; k < 4; ++k)
            o[k] = __builtin_bit_cast(half2_t, __builtin_amdgcn_alignbit(
                       __builtin_bit_cast(unsigned, e[k + 1]),
                       __builtin_bit_cast(unsigned, e[k]), 16));
        o[4] = pk(t[9], 0.0f);
    };

    // Dot pass with compile-time ring phase R: kernel row i updates physical
    // slot (R+6-i)%7; slot R completes as output row yi-3.
    auto dots = [&](auto Rc) {
        constexpr int R = decltype(Rc)::value;
        // Keep per-pass LDS weight reads in the loop (hoisting 28 pairs would
        // blow the 64-VGPR tier and spill).
        asm volatile("" ::: "memory");
        #pragma unroll
        for (int i = 0; i < KH; ++i) {
            const uint4 wq = *(const uint4*)(wlds + i * 4);   // kernel row i
            const int s = (R + 6 - i) % 7;                    // compile-time
            #pragma unroll
            for (int xo = 0; xo < XPT; ++xo) {
                float a = acc[s][xo];
                if ((xo & 1) == 0) {
                    const int k0 = xo >> 1;
                    a = dot2f(wq.x, e[k0],     a);
                    a = dot2f(wq.y, e[k0 + 1], a);
                    a = dot2f(wq.z, e[k0 + 2], a);
                    a = dot2f(wq.w, e[k0 + 3], a);
                } else {
                    const int k0 = (xo - 1) >> 1;
                    a = dot2f(wq.x, o[k0],     a);
                    a = dot2f(wq.y, o[k0 + 1], a);
                    a = dot2f(wq.z, o[k0 + 2], a);
                    a = dot2f(wq.w, o[k0 + 3], a);
                }
                acc[s][xo] = a;
            }
        }
    };

    // Prologue: load + pack row yi0 (one exposed wait).
    issue_taps(t, yi0);
    pack();

    // Main: 5 x 7 static passes, no ring shift.
    #pragma unroll 1
    for (int it = 0; it < 5; ++it) {
        const int yb = yi0 + it * 7;
        auto body = [&](auto Rc) {
            constexpr int R = decltype(Rc)::value;
            const int yi = yb + R;
            issue_taps(t, yi + 1);        // next row; consumed at pack below
            dots(Rc);
            const int y = yi - 3;
            if (y >= y0) {                // p<=34 -> y<=y0+28, in range
                float* orow = ob + ((size_t)y * WW + x0) * CC + c;
                #pragma unroll
                for (int xo = 0; xo < XPT; ++xo)
                    orow[xo * CC] = acc[R][xo];
            }
            #pragma unroll
            for (int xo = 0; xo < XPT; ++xo) acc[R][xo] = 0.0f;
            pack();
            __builtin_amdgcn_sched_barrier(0);   // contain regs per pass (R9 fix)
        };
        body(ic<0>{}); body(ic<1>{}); body(ic<2>{}); body(ic<3>{});
        body(ic<4>{}); body(ic<5>{}); body(ic<6>{});
    }

    // Tail: 3 canonical shifting passes (ring is back at phase 0 after 35).
    #pragma unroll 1
    for (int p = 35; p < NPASS; ++p) {
        const int yi = yi0 + p;
        issue_taps(t, yi + 1);            // last iteration loads row y0+35 (or
                                          // zero-path if >=HH); result unused
        dots(ic<0>{});
        const int y = yi - 3;
        {   // y in [y0+29, y0+31] here, always valid
            float* orow = ob + ((size_t)y * WW + x0) * CC + c;
            #pragma unroll
            for (int xo = 0; xo < XPT; ++xo)
                orow[xo * CC] = acc[0][xo];
        }
        #pragma unroll
        for (int s = 0; s < KH - 1; ++s)
            #pragma unroll
            for (int xo = 0; xo < XPT; ++xo) acc[s][xo] = acc[s + 1][xo];
        #pragma unroll
        for (int xo = 0; xo < XPT; ++xo) acc[KH - 1][xo] = 0.0f;
        pack();
        __builtin_amdgcn_sched_barrier(0);
    }
}

extern "C" void kernel_launch(void* const* d_in, const int* in_sizes, int n_in,
                              void* d_out, int out_size, void* d_ws, size_t ws_size,
                              hipStream_t stream) {
    const float* in  = (const float*)d_in[0];
    const float* ker = (const float*)d_in[1];
    float*       out = (float*)d_out;

    crossconv_kernel<<<GRID, 1024, 0, stream>>>(in, ker, out);
}

// Round 14
// 139.840 us; speedup vs baseline: 3.2877x; 3.2877x over previous
//
#include <hip/hip_runtime.h>

// Per-sample depthwise 7x7 cross-correlation, NHWC, SAME padding.
// inputs:  [B,H,W,C] fp32, kernels: [B,7,7,C] fp32, out: [B,H,W,C] fp32.
// out[b,y,x,c] = sum_{i,j} in[b, y+i-3, x+j-3, c] * ker[b,i,j,c]  (zero pad)
//
// R14 = R8 (fp16 dot2, weights packed in LDS, dynamic 7-slot ring, 64-VGPR
// tier) with FINER DISPATCH GRAIN: 512-thread blocks, 4 blocks/CU (same 32
// waves/CU, twice the scheduling units -> better SIMD balance; tests the
// occupancy-starvation theory behind the 143us plateau). Plus two safe
// micro-opts: tap base rebased to col x0-1 (10 loads use 13-bit immediate
// offsets, one base add per pass) and o[] derived from e[] via v_alignbit.
// NO multi-pass unrolling (R9/R13: allocator spills), NO occupancy
// attributes (R2/R6: forced spills).

#define BB 32
#define HH 128
#define WW 128
#define CC 128
#define KH 7
#define KW 7

#define XPT 4                        // x outputs per thread
#define NTAP (XPT + KW - 1)          // 10 tap columns per thread
#define XG 4                         // x-groups per block (512 threads / 128 c)
#define SLABW (XG * XPT)             // 16 output columns per block
#define NXS (WW / SLABW)             // 8 x-slabs
#define YSPLIT 4
#define YROWS (HH / YSPLIT)          // 32 output rows per block
#define GRID (BB * NXS * YSPLIT)     // 1024 blocks = 4 per CU
#define WSLOTS 28                    // per-c packed-weight uints (7 rows x 4 pairs)
#define NPASS (YROWS + KH - 1)       // 38 single-row passes

typedef _Float16 half2_t __attribute__((ext_vector_type(2)));

static __device__ __forceinline__ half2_t pk(float a, float b) {
#if __has_builtin(__builtin_amdgcn_cvt_pkrtz)
    return __builtin_bit_cast(half2_t, __builtin_amdgcn_cvt_pkrtz(a, b));
#else
    half2_t r; r.x = (_Float16)a; r.y = (_Float16)b; return r;
#endif
}

static __device__ __forceinline__ float dot2f(unsigned w, half2_t t, float c) {
#if __has_builtin(__builtin_amdgcn_fdot2)
    return __builtin_amdgcn_fdot2(__builtin_bit_cast(half2_t, w), t, c, false);
#else
    half2_t wv = __builtin_bit_cast(half2_t, w);
    return fmaf((float)wv.x, (float)t.x, fmaf((float)wv.y, (float)t.y, c));
#endif
}

__global__ __launch_bounds__(512) void crossconv_kernel(
    const float* __restrict__ in,
    const float* __restrict__ ker,
    float* __restrict__ out)
{
    __shared__ unsigned lds_w[CC * WSLOTS];   // 14336 B

    const int tid = threadIdx.x;
    const int c  = tid & (CC - 1);   // lanes contiguous in c -> coalesced
    const int xg = __builtin_amdgcn_readfirstlane(tid >> 7);   // 0..3, wave-uniform

    // Bijective XCD swizzle (GRID=1024, 128 blocks/XCD = 4 whole samples).
    const int bid = blockIdx.x;
    const int swz = (bid & 7) * (GRID / 8) + (bid >> 3);
    const int b  = swz >> 5;         // 32 blocks per sample (8 xs x 4 yh)
    const int xs = (swz >> 2) & 7;
    const int yh = swz & 3;
    const int x0 = xs * SLABW + xg * XPT;  // wave-uniform (scalar)
    const int y0 = yh * YROWS;

    // Stage packed weights into LDS: slot s (0..27) -> row i=s>>2, pair q=s&3.
    // q<3: (w[i][2q], w[i][2q+1]); q==3: (w[i][6], 0).
    {
        const float* kb = ker + ((size_t)b * KH * KW) * CC + c;
        for (int s = xg; s < WSLOTS; s += XG) {
            const int i = s >> 2, q = s & 3;
            half2_t pr;
            if (q < 3) {
                const int f0 = i * KW + 2 * q;
                pr = pk(kb[f0 * CC], kb[(f0 + 1) * CC]);
            } else {
                pr = pk(kb[(i * KW + 6) * CC], 0.0f);
            }
            lds_w[c * WSLOTS + s] = __builtin_bit_cast(unsigned, pr);
        }
    }
    __syncthreads();

    const float* ib = in  + ((size_t)b * HH * WW) * CC;
    float*       ob = out + ((size_t)b * HH * WW) * CC;
    const unsigned* wlds = &lds_w[c * WSLOTS];

    const bool interior = (x0 >= 3) && (x0 + XPT + 2 < WW);

    // Issue the 10 tap loads for row yi. Base rebased to column x0-1 so the
    // per-tap offsets (j-2)*512 B fall in [-1024, 3584] -> 13-bit immediates,
    // one 64-bit base add per pass.
    auto load_taps = [&](float* t, int yi) {
        if (yi < 0 || yi >= HH) {
            #pragma unroll
            for (int j = 0; j < NTAP; ++j) t[j] = 0.0f;
            return;
        }
        const float* base = ib + (size_t)yi * WW * CC + (x0 - 1) * CC + c;
        if (interior) {
            #pragma unroll
            for (int j = 0; j < NTAP; ++j)
                t[j] = base[(j - 2) * CC];                 // imm offsets
        } else {
            #pragma unroll
            for (int j = 0; j < NTAP; ++j) {
                const int xx = x0 - 3 + j;
                t[j] = (xx >= 0 && xx < WW) ? base[(j - 2) * CC] : 0.0f;
            }
        }
    };

    // Sliding ring: acc[s][xo] partial for output row y = yi-3+s.
    float acc[KH][XPT];
    #pragma unroll
    for (int s = 0; s < KH; ++s)
        #pragma unroll
        for (int xo = 0; xo < XPT; ++xo) acc[s][xo] = 0.0f;

    const int yi0 = y0 - 3;

    // Packed taps for the CURRENT pass row:
    // e[k]=(t[2k],t[2k+1]) k=0..4 ; o[k]=(t[2k+1],t[2k+2]) via alignbit;
    // o[4]=(t9,0). Even xo: e[xo/2+q]; odd xo: o[(xo-1)/2+q].
    float t[NTAP];
    half2_t e[5], o[5];
    load_taps(t, yi0);
    #pragma unroll
    for (int k = 0; k < 5; ++k) e[k] = pk(t[2 * k], t[2 * k + 1]);
    #pragma unroll
    for (int k = 0; k < 4; ++k)
        o[k] = __builtin_bit_cast(half2_t, __builtin_amdgcn_alignbit(
                   __builtin_bit_cast(unsigned, e[k + 1]),
                   __builtin_bit_cast(unsigned, e[k]), 16));
    o[4] = pk(t[9], 0.0f);

    #pragma unroll 1
    for (int p = 0; p < NPASS; ++p) {
        const int yi = yi0 + p;

        // Issue next row's tap loads; the dot pass hides the latency.
        load_taps(t, (p + 1 < NPASS) ? (yi + 1) : HH);

        // Keep per-pass LDS weight reads in the loop (hoisting 28 pairs would
        // blow the 64-VGPR tier and spill).
        asm volatile("" ::: "memory");

        #pragma unroll
        for (int i = 0; i < KH; ++i) {
            const uint4 wq = *(const uint4*)(wlds + i * 4);   // kernel row i
            const int s = 6 - i;
            #pragma unroll
            for (int xo = 0; xo < XPT; ++xo) {
                float a = acc[s][xo];
                if ((xo & 1) == 0) {
                    const int k0 = xo >> 1;
                    a = dot2f(wq.x, e[k0],     a);
                    a = dot2f(wq.y, e[k0 + 1], a);
                    a = dot2f(wq.z, e[k0 + 2], a);
                    a = dot2f(wq.w, e[k0 + 3], a);
                } else {
                    const int k0 = (xo - 1) >> 1;
                    a = dot2f(wq.x, o[k0],     a);
                    a = dot2f(wq.y, o[k0 + 1], a);
                    a = dot2f(wq.z, o[k0 + 2], a);
                    a = dot2f(wq.w, o[k0 + 3], a);
                }
                acc[s][xo] = a;
            }
        }

        const int y = yi - 3;
        if (y >= y0) {                       // upper bound guaranteed by loop end
            float* orow = ob + ((size_t)y * WW + x0) * CC + c;
            #pragma unroll
            for (int xo = 0; xo < XPT; ++xo)
                orow[xo * CC] = acc[0][xo];
        }

        // Shift ring, open fresh top slot.
        #pragma unroll
        for (int s = 0; s < KH - 1; ++s)
            #pragma unroll
            for (int xo = 0; xo < XPT; ++xo) acc[s][xo] = acc[s + 1][xo];
        #pragma unroll
        for (int xo = 0; xo < XPT; ++xo) acc[KH - 1][xo] = 0.0f;

        // Pack the prefetched row for the next pass.
        #pragma unroll
        for (int k = 0; k < 5; ++k) e[k] = pk(t[2 * k], t[2 * k + 1]);
        #pragma unroll
        for (int k = 0; k < 4; ++k)
            o[k] = __builtin_bit_cast(half2_t, __builtin_amdgcn_alignbit(
                       __builtin_bit_cast(unsigned, e[k + 1]),
                       __builtin_bit_cast(unsigned, e[k]), 16));
        o[4] = pk(t[9], 0.0f);
    }
}

extern "C" void kernel_launch(void* const* d_in, const int* in_sizes, int n_in,
                              void* d_out, int out_size, void* d_ws, size_t ws_size,
                              hipStream_t stream) {
    const float* in  = (const float*)d_in[0];
    const float* ker = (const float*)d_in[1];
    float*       out = (float*)d_out;

    crossconv_kernel<<<GRID, 512, 0, stream>>>(in, ker, out);
}